// Round 7
// baseline (303.804 us; speedup 1.0000x reference)
//
#include <hip/hip_runtime.h>

typedef unsigned short u16;
typedef unsigned int u32;
typedef __bf16 bf16x8 __attribute__((ext_vector_type(8)));
typedef float f32x4 __attribute__((ext_vector_type(4)));

#define AS1 __attribute__((address_space(1)))
#define AS3 __attribute__((address_space(3)))

// XOR-swizzle for 128B-row LDS tiles (T2): flips byte bits 4-6 with row&7
#define SWZB(x) ((x) ^ ((((x) >> 7) & 7) << 4))

__device__ __forceinline__ float bf2f(u16 u) {
    union { u32 i; float f; } v; v.i = ((u32)u) << 16; return v.f;
}
__device__ __forceinline__ u16 f2bf(float f) {
    union { float f; u32 i; } v; v.f = f;
    u32 i = v.i;
    u32 r = (i + 0x7fffu + ((i >> 16) & 1u)) >> 16;
    return (u16)r;
}
__device__ __forceinline__ u32 cvtpk_bf16(float lo, float hi) {
    u32 r;
    asm("v_cvt_pk_bf16_f32 %0, %1, %2" : "=v"(r) : "v"(lo), "v"(hi));
    return r;
}
__device__ __forceinline__ void gload_lds16(const u16* src, u16* dst) {
    __builtin_amdgcn_global_load_lds((const AS1 void*)src, (AS3 void*)dst, 16, 0, 0);
}

// ---------------------------------------------------------------- transpose
// 1024x1024 fp32 -> bf16 transpose: out[j][i] = (bf16)in[i][j]
__global__ __launch_bounds__(256) void transpose1024(const float* __restrict__ in,
                                                     u16* __restrict__ out) {
    __shared__ u16 t[64][65];
    int c = threadIdx.x & 63, r0 = threadIdx.x >> 6;
    int ib = blockIdx.y * 64, jb = blockIdx.x * 64;
    #pragma unroll
    for (int r = r0; r < 64; r += 4) t[r][c] = f2bf(in[(size_t)(ib + r) * 1024 + jb + c]);
    __syncthreads();
    #pragma unroll
    for (int r = r0; r < 64; r += 4) out[(size_t)(jb + r) * 1024 + ib + c] = t[c][r];
}

// V transpose: qkv[(b*2048+t)*3072 + 2048 + h*64 + dh] -> vT[(bh*64+dh)*2048 + t]
__global__ __launch_bounds__(256) void vtrans(const u16* __restrict__ qkv,
                                              u16* __restrict__ vT) {
    int bh = blockIdx.y, b = bh >> 4, h = bh & 15;
    int t0 = blockIdx.x * 64;
    __shared__ u16 tl[64][65];
    int c = threadIdx.x & 63, r0 = threadIdx.x >> 6;
    const u16* src = qkv + ((size_t)(b * 2048 + t0)) * 3072 + 2048 + h * 64;
    #pragma unroll
    for (int r = r0; r < 64; r += 4) tl[r][c] = src[(size_t)r * 3072 + c];
    __syncthreads();
    u16* dst = vT + ((size_t)bh * 64) * 2048 + t0;
    #pragma unroll
    for (int r = r0; r < 64; r += 4) dst[(size_t)r * 2048 + c] = tl[c][r];
}

// ---------------------------------------------------------------- layernorm
__global__ __launch_bounds__(256) void ln_kernel(const float* __restrict__ x,
                                                 const float* __restrict__ g,
                                                 const float* __restrict__ bb,
                                                 u16* __restrict__ xn) {
    int row = blockIdx.x;
    int tid = threadIdx.x;
    const float* xr = x + (size_t)row * 1024;
    float4 v = *(const float4*)&xr[tid * 4];
    float f0 = v.x, f1 = v.y, f2 = v.z, f3 = v.w;
    float s = f0 + f1 + f2 + f3;
    float sq = f0 * f0 + f1 * f1 + f2 * f2 + f3 * f3;
    #pragma unroll
    for (int m = 1; m < 64; m <<= 1) { s += __shfl_xor(s, m, 64); sq += __shfl_xor(sq, m, 64); }
    __shared__ float red[8];
    int wid = tid >> 6, lane = tid & 63;
    if (lane == 0) { red[wid] = s; red[4 + wid] = sq; }
    __syncthreads();
    s = red[0] + red[1] + red[2] + red[3];
    sq = red[4] + red[5] + red[6] + red[7];
    float mu = s * (1.f / 1024.f);
    float var = sq * (1.f / 1024.f) - mu * mu;
    float rs = rsqrtf(var + 1e-5f);
    float4 gv = *(const float4*)&g[tid * 4];
    float4 bv = *(const float4*)&bb[tid * 4];
    ushort4 o;
    o.x = f2bf((f0 - mu) * rs * gv.x + bv.x);
    o.y = f2bf((f1 - mu) * rs * gv.y + bv.y);
    o.z = f2bf((f2 - mu) * rs * gv.z + bv.z);
    o.w = f2bf((f3 - mu) * rs * gv.w + bv.w);
    *(ushort4*)&xn[(size_t)row * 1024 + tid * 4] = o;
}

// ---------------------------------------------------------------- GEMM (B^T)
// C[m][n] = sum_k A[m][k]*BT[n][k]; ext=0: bf16 out; ext=1: fp32 out + bias.
__global__ __launch_bounds__(256) void gemm_bt(const u16* __restrict__ A,
                                               const u16* __restrict__ BT,
                                               u16* __restrict__ C16,
                                               float* __restrict__ C32,
                                               const float* __restrict__ bias,
                                               int K, int ldc, int ext) {
    __shared__ __align__(16) u16 lA[128 * 32];
    __shared__ __align__(16) u16 lB[128 * 32];
    int tid = threadIdx.x, lane = tid & 63, wid = tid >> 6;
    int wr = wid >> 1, wc = wid & 1;
    int m0 = blockIdx.y * 128, n0 = blockIdx.x * 128;
    int l4 = lane >> 4, l15 = lane & 15;

    f32x4 acc[4][4] = {};
    int NT = K >> 5;

    auto stage = [&](int kt) {
        int k0 = kt << 5;
        #pragma unroll
        for (int i = 0; i < 2; ++i) {
            int j = wid * 2 + i;
            int row = j * 16 + (lane >> 2);
            int ch = (lane & 3) * 8;
            gload_lds16(A + (size_t)(m0 + row) * K + k0 + ch, &lA[j * 512]);
            gload_lds16(BT + (size_t)(n0 + row) * K + k0 + ch, &lB[j * 512]);
        }
    };
    stage(0);
    for (int kt = 0; kt < NT; ++kt) {
        __syncthreads();
        bf16x8 af[4], bfr[4];
        #pragma unroll
        for (int i = 0; i < 4; ++i) {
            af[i]  = *(const bf16x8*)&lA[(wr * 64 + i * 16 + l15) * 32 + l4 * 8];
            bfr[i] = *(const bf16x8*)&lB[(wc * 64 + i * 16 + l15) * 32 + l4 * 8];
        }
        __syncthreads();
        if (kt + 1 < NT) stage(kt + 1);
        #pragma unroll
        for (int i = 0; i < 4; ++i)
            #pragma unroll
            for (int j = 0; j < 4; ++j)
                acc[i][j] = __builtin_amdgcn_mfma_f32_16x16x32_bf16(af[i], bfr[j], acc[i][j], 0, 0, 0);
    }
    #pragma unroll
    for (int j = 0; j < 4; ++j) {
        int col = n0 + wc * 64 + j * 16 + l15;
        float bv = ext ? bias[col] : 0.f;
        #pragma unroll
        for (int i = 0; i < 4; ++i) {
            #pragma unroll
            for (int r = 0; r < 4; ++r) {
                int row = m0 + wr * 64 + i * 16 + l4 * 4 + r;
                float val = acc[i][j][r] + bv;
                if (ext) C32[(size_t)row * ldc + col] = val;
                else     C16[(size_t)row * ldc + col] = f2bf(val);
            }
        }
    }
}

// ---------------------------------------------------------------- attention
// Swapped QK^T (S = mfma(K,Q): q lane-local) + K-row PERMUTED staging so the
// softmax output packs (cvt_pk) directly into PV A-fragments: P never touches
// LDS. Double-buffered K/V LDS -> 1 barrier/tile. No max-shift (args bounded).
// Grid: 1D with XCD-slab mapping — XCD x owns qt in [4x,4x+4); within an XCD
// blocks run qt-inner/bh-outer so the 2MB mask slab stays hot in that XCD's
// L2 and each bh's 512KB K/V is used by 4 adjacent blocks.
__global__ __launch_bounds__(256) void attn_kernel(const u16* __restrict__ qkv,
                                                   const u16* __restrict__ vT,
                                                   const float* __restrict__ mask,
                                                   u16* __restrict__ av) {
    __shared__ __align__(16) u16 lK[2][64 * 64];   // [kv][dh], rows permuted+swizzled
    __shared__ __align__(16) u16 lV[2][64 * 64];   // [dh][kv], swizzled
    int bid = blockIdx.x;
    int xcd = bid & 7, loc = bid >> 3;
    int qt = xcd * 4 + (loc & 3);      // qt slab per XCD (mask L2-resident)
    int bh = loc >> 2;                 // bh outer within XCD (K/V reused 4x)
    int b = bh >> 4, h = bh & 15;
    int tid = threadIdx.x, lane = tid & 63, wid = tid >> 6;
    int l4 = lane >> 4, l15 = lane & 15;
    int q0 = qt * 64;
    int qlane = q0 + wid * 16 + l15;   // this lane's q-row

    const u16* qb = qkv + (size_t)(b * 2048 + qlane) * 3072 + h * 64;
    bf16x8 qf0 = *(const bf16x8*)&qb[l4 * 8];
    bf16x8 qf1 = *(const bf16x8*)&qb[32 + l4 * 8];
    const float* mrow = mask + (size_t)qlane * 2048 + 8 * l4;  // l4 offset baked in

    f32x4 o[4] = {};
    float lsum = 0.f;

    // staging chunks: chunk c = 16B covering row c>>3, dh/kv (c&7)*8
    int c0 = tid, c1 = 256 + tid;
    // K-row permutation: global row g -> LDS row p(g) so that the QK^T C-frag
    // k-order matches the PV A-frag k-order (k = 32*(fj>>1)+8*l4+4*(fj&1)+r).
    auto pmap = [](int g) {
        return (g & 32) + 4 * ((g >> 3) & 3) + (g & 3) + ((g & 4) << 2);
    };
    int kd0 = SWZB(pmap(c0 >> 3) * 128 + (c0 & 7) * 16);
    int kd1 = SWZB(pmap(c1 >> 3) * 128 + (c1 & 7) * 16);
    int vd0 = SWZB((c0 >> 3) * 128 + (c0 & 7) * 16);
    int vd1 = SWZB((c1 >> 3) * 128 + (c1 & 7) * 16);
    const u16* ksrc0 = qkv + (size_t)(b * 2048 + (c0 >> 3)) * 3072 + 1024 + h * 64 + (c0 & 7) * 8;
    const u16* ksrc1 = qkv + (size_t)(b * 2048 + (c1 >> 3)) * 3072 + 1024 + h * 64 + (c1 & 7) * 8;
    const u16* vsrc0 = vT + (size_t)(bh * 64 + (c0 >> 3)) * 2048 + (c0 & 7) * 8;
    const u16* vsrc1 = vT + (size_t)(bh * 64 + (c1 >> 3)) * 2048 + (c1 & 7) * 8;

    auto loadKV = [&](int t, bf16x8& K0, bf16x8& K1, bf16x8& V0, bf16x8& V1) {
        size_t ko = (size_t)t * (64 * 3072);
        int vo = t * 64;
        K0 = *(const bf16x8*)(ksrc0 + ko);
        K1 = *(const bf16x8*)(ksrc1 + ko);
        V0 = *(const bf16x8*)(vsrc0 + vo);
        V1 = *(const bf16x8*)(vsrc1 + vo);
    };

    auto body = [&](int t, int pbuf,
                    bf16x8& cK0, bf16x8& cK1, bf16x8& cV0, bf16x8& cV1,
                    bf16x8& nK0, bf16x8& nK1, bf16x8& nV0, bf16x8& nV1) {
        // stage current tile into buf[pbuf] (prev barrier guarantees it's free)
        *(bf16x8*)((char*)lK[pbuf] + kd0) = cK0;
        *(bf16x8*)((char*)lK[pbuf] + kd1) = cK1;
        *(bf16x8*)((char*)lV[pbuf] + vd0) = cV0;
        *(bf16x8*)((char*)lV[pbuf] + vd1) = cV1;
        __syncthreads();  // single barrier per tile (dbuf makes this sound)
        if (t + 1 < 32) loadKV(t + 1, nK0, nK1, nV0, nV1);  // cross-tile prefetch
        // mask for this tile (consumed after QK^T: ~400cyc of cover)
        int k0 = t * 64;
        f32x4 mm[4];
        mm[0] = *(const f32x4*)(mrow + k0);
        mm[1] = *(const f32x4*)(mrow + k0 + 4);
        mm[2] = *(const f32x4*)(mrow + k0 + 32);
        mm[3] = *(const f32x4*)(mrow + k0 + 36);
        // S = mfma(K, Q): C[row = permuted k][col = q = l15]
        const char* Kb = (const char*)lK[pbuf];
        f32x4 s[4] = {};
        #pragma unroll
        for (int fj = 0; fj < 4; ++fj) {
            bf16x8 kf0 = *(const bf16x8*)(Kb + SWZB((fj * 16 + l15) * 128 + l4 * 16));
            bf16x8 kf1 = *(const bf16x8*)(Kb + SWZB((fj * 16 + l15) * 128 + 64 + l4 * 16));
            s[fj] = __builtin_amdgcn_mfma_f32_16x16x32_bf16(kf0, qf0, s[fj], 0, 0, 0);
            s[fj] = __builtin_amdgcn_mfma_f32_16x16x32_bf16(kf1, qf1, s[fj], 0, 0, 0);
        }
        // P = exp(S*SCALE*mask), packed straight into PV A-fragments
        union PU { u32 u[4]; bf16x8 v; };
        PU pa[2];
        #pragma unroll
        for (int fj = 0; fj < 4; ++fj) {
            float p0 = __expf(s[fj][0] * 0.125f * mm[fj][0]);
            float p1 = __expf(s[fj][1] * 0.125f * mm[fj][1]);
            float p2 = __expf(s[fj][2] * 0.125f * mm[fj][2]);
            float p3 = __expf(s[fj][3] * 0.125f * mm[fj][3]);
            lsum += (p0 + p1) + (p2 + p3);
            int ks = fj >> 1, hf = (fj & 1) * 2;
            pa[ks].u[hf]     = cvtpk_bf16(p0, p1);
            pa[ks].u[hf + 1] = cvtpk_bf16(p2, p3);
        }
        // O += P V
        const char* Vb = (const char*)lV[pbuf];
        #pragma unroll
        for (int ks = 0; ks < 2; ++ks) {
            #pragma unroll
            for (int fj = 0; fj < 4; ++fj) {
                bf16x8 vf = *(const bf16x8*)(Vb + SWZB((fj * 16 + l15) * 128 + ks * 64 + l4 * 16));
                o[fj] = __builtin_amdgcn_mfma_f32_16x16x32_bf16(pa[ks].v, vf, o[fj], 0, 0, 0);
            }
        }
    };

    bf16x8 ka0, ka1, va0, va1, kb0, kb1, vb0, vb1;
    loadKV(0, ka0, ka1, va0, va1);
    for (int t = 0; t < 32; t += 2) {
        body(t,     0, ka0, ka1, va0, va1, kb0, kb1, vb0, vb1);
        body(t + 1, 1, kb0, kb1, vb0, vb1, ka0, ka1, va0, va1);
    }

    // rowsum: reduce over the 4 l4-groups (same q=l15 column)
    lsum += __shfl_xor(lsum, 16, 64);
    lsum += __shfl_xor(lsum, 32, 64);
    // output rows are q = l4*4+r; lsum lives at lane with l15==q
    float denom[4];
    #pragma unroll
    for (int r = 0; r < 4; ++r) denom[r] = __shfl(lsum, l4 * 4 + r, 64);
    int qrow = q0 + wid * 16;
    #pragma unroll
    for (int fj = 0; fj < 4; ++fj) {
        #pragma unroll
        for (int r = 0; r < 4; ++r) {
            av[(size_t)(b * 2048 + qrow + l4 * 4 + r) * 1024 + h * 64 + fj * 16 + l15] =
                f2bf(o[fj][r] / denom[r]);
        }
    }
}

// ---------------------------------------------------------------- launch
extern "C" void kernel_launch(void* const* d_in, const int* in_sizes, int n_in,
                              void* d_out, int out_size, void* d_ws, size_t ws_size,
                              hipStream_t stream) {
    (void)in_sizes; (void)n_in; (void)out_size; (void)ws_size;
    const float* x     = (const float*)d_in[0];
    const float* mask  = (const float*)d_in[1];
    const float* gamma = (const float*)d_in[2];
    const float* beta  = (const float*)d_in[3];
    const float* Wq    = (const float*)d_in[4];
    const float* Wk    = (const float*)d_in[5];
    const float* Wv    = (const float*)d_in[6];
    const float* Wo    = (const float*)d_in[7];
    const float* bo    = (const float*)d_in[8];

    char* ws = (char*)d_ws;
    u16* xn   = (u16*)(ws);                                   // 16.8 MB (reused as av)
    u16* WT   = (u16*)(ws + 16777216);                        // 6.29 MB [3072][1024]
    u16* WoT  = (u16*)(ws + 16777216 + 6291456);              // 2.10 MB
    u16* qkvb = (u16*)(ws + 16777216 + 6291456 + 2097152);    // 50.33 MB [8192][3072]
    u16* vT   = (u16*)(ws + 16777216 + 6291456 + 2097152 + 50331648);  // 16.8 MB
    u16* av = xn;  // xn dead after QKV GEMM

    dim3 tb(256);
    transpose1024<<<dim3(16, 16), tb, 0, stream>>>(Wq, WT);
    transpose1024<<<dim3(16, 16), tb, 0, stream>>>(Wk, WT + 1024 * 1024);
    transpose1024<<<dim3(16, 16), tb, 0, stream>>>(Wv, WT + 2 * 1024 * 1024);
    transpose1024<<<dim3(16, 16), tb, 0, stream>>>(Wo, WoT);
    ln_kernel<<<8192, tb, 0, stream>>>(x, gamma, beta, xn);
    gemm_bt<<<dim3(24, 64), tb, 0, stream>>>(xn, WT, qkvb, nullptr, nullptr, 1024, 3072, 0);
    vtrans<<<dim3(32, 64), tb, 0, stream>>>(qkvb, vT);
    attn_kernel<<<2048, tb, 0, stream>>>(qkvb, vT, mask, av);
    gemm_bt<<<dim3(8, 64), tb, 0, stream>>>(av, WoT, nullptr, (float*)d_out, bo, 1024, 1024, 1);
}

// Round 8
// 284.038 us; speedup vs baseline: 1.0696x; 1.0696x over previous
//
#include <hip/hip_runtime.h>

typedef unsigned short u16;
typedef unsigned int u32;
typedef __bf16 bf16x8 __attribute__((ext_vector_type(8)));
typedef float f32x4 __attribute__((ext_vector_type(4)));

#define AS1 __attribute__((address_space(1)))
#define AS3 __attribute__((address_space(3)))

// XOR-swizzle for 128B-row LDS tiles (T2): flips byte bits 4-6 with row&7
#define SWZB(x) ((x) ^ ((((x) >> 7) & 7) << 4))

__device__ __forceinline__ float bf2f(u16 u) {
    union { u32 i; float f; } v; v.i = ((u32)u) << 16; return v.f;
}
__device__ __forceinline__ u16 f2bf(float f) {
    union { float f; u32 i; } v; v.f = f;
    u32 i = v.i;
    u32 r = (i + 0x7fffu + ((i >> 16) & 1u)) >> 16;
    return (u16)r;
}
__device__ __forceinline__ u32 cvtpk_bf16(float lo, float hi) {
    u32 r;
    asm("v_cvt_pk_bf16_f32 %0, %1, %2" : "=v"(r) : "v"(lo), "v"(hi));
    return r;
}
__device__ __forceinline__ void gload_lds16(const u16* src, u16* dst) {
    __builtin_amdgcn_global_load_lds((const AS1 void*)src, (AS3 void*)dst, 16, 0, 0);
}

// ---------------------------------------------------------------- transpose
// 1024x1024 fp32 -> bf16 transpose with scale: out[j][i] = (bf16)(in[i][j]*scale)
__global__ __launch_bounds__(256) void transpose1024(const float* __restrict__ in,
                                                     u16* __restrict__ out,
                                                     float scale) {
    __shared__ u16 t[64][65];
    int c = threadIdx.x & 63, r0 = threadIdx.x >> 6;
    int ib = blockIdx.y * 64, jb = blockIdx.x * 64;
    #pragma unroll
    for (int r = r0; r < 64; r += 4)
        t[r][c] = f2bf(in[(size_t)(ib + r) * 1024 + jb + c] * scale);
    __syncthreads();
    #pragma unroll
    for (int r = r0; r < 64; r += 4) out[(size_t)(jb + r) * 1024 + ib + c] = t[c][r];
}

// V transpose: qkv[(b*2048+t)*3072 + 2048 + h*64 + dh] -> vT[(bh*64+dh)*2048 + t]
__global__ __launch_bounds__(256) void vtrans(const u16* __restrict__ qkv,
                                              u16* __restrict__ vT) {
    int bh = blockIdx.y, b = bh >> 4, h = bh & 15;
    int t0 = blockIdx.x * 64;
    __shared__ u16 tl[64][65];
    int c = threadIdx.x & 63, r0 = threadIdx.x >> 6;
    const u16* src = qkv + ((size_t)(b * 2048 + t0)) * 3072 + 2048 + h * 64;
    #pragma unroll
    for (int r = r0; r < 64; r += 4) tl[r][c] = src[(size_t)r * 3072 + c];
    __syncthreads();
    u16* dst = vT + ((size_t)bh * 64) * 2048 + t0;
    #pragma unroll
    for (int r = r0; r < 64; r += 4) dst[(size_t)r * 2048 + c] = tl[c][r];
}

// ---------------------------------------------------------------- layernorm
__global__ __launch_bounds__(256) void ln_kernel(const float* __restrict__ x,
                                                 const float* __restrict__ g,
                                                 const float* __restrict__ bb,
                                                 u16* __restrict__ xn) {
    int row = blockIdx.x;
    int tid = threadIdx.x;
    const float* xr = x + (size_t)row * 1024;
    float4 v = *(const float4*)&xr[tid * 4];
    float f0 = v.x, f1 = v.y, f2 = v.z, f3 = v.w;
    float s = f0 + f1 + f2 + f3;
    float sq = f0 * f0 + f1 * f1 + f2 * f2 + f3 * f3;
    #pragma unroll
    for (int m = 1; m < 64; m <<= 1) { s += __shfl_xor(s, m, 64); sq += __shfl_xor(sq, m, 64); }
    __shared__ float red[8];
    int wid = tid >> 6, lane = tid & 63;
    if (lane == 0) { red[wid] = s; red[4 + wid] = sq; }
    __syncthreads();
    s = red[0] + red[1] + red[2] + red[3];
    sq = red[4] + red[5] + red[6] + red[7];
    float mu = s * (1.f / 1024.f);
    float var = sq * (1.f / 1024.f) - mu * mu;
    float rs = rsqrtf(var + 1e-5f);
    float4 gv = *(const float4*)&g[tid * 4];
    float4 bv = *(const float4*)&bb[tid * 4];
    ushort4 o;
    o.x = f2bf((f0 - mu) * rs * gv.x + bv.x);
    o.y = f2bf((f1 - mu) * rs * gv.y + bv.y);
    o.z = f2bf((f2 - mu) * rs * gv.z + bv.z);
    o.w = f2bf((f3 - mu) * rs * gv.w + bv.w);
    *(ushort4*)&xn[(size_t)row * 1024 + tid * 4] = o;
}

// ---------------------------------------------------------------- GEMM (B^T)
// C[m][n] = sum_k A[m][k]*BT[n][k]; ext=0: bf16 out; ext=1: fp32 out + bias.
__global__ __launch_bounds__(256) void gemm_bt(const u16* __restrict__ A,
                                               const u16* __restrict__ BT,
                                               u16* __restrict__ C16,
                                               float* __restrict__ C32,
                                               const float* __restrict__ bias,
                                               int K, int ldc, int ext) {
    __shared__ __align__(16) u16 lA[128 * 32];
    __shared__ __align__(16) u16 lB[128 * 32];
    int tid = threadIdx.x, lane = tid & 63, wid = tid >> 6;
    int wr = wid >> 1, wc = wid & 1;
    int m0 = blockIdx.y * 128, n0 = blockIdx.x * 128;
    int l4 = lane >> 4, l15 = lane & 15;

    f32x4 acc[4][4] = {};
    int NT = K >> 5;

    auto stage = [&](int kt) {
        int k0 = kt << 5;
        #pragma unroll
        for (int i = 0; i < 2; ++i) {
            int j = wid * 2 + i;
            int row = j * 16 + (lane >> 2);
            int ch = (lane & 3) * 8;
            gload_lds16(A + (size_t)(m0 + row) * K + k0 + ch, &lA[j * 512]);
            gload_lds16(BT + (size_t)(n0 + row) * K + k0 + ch, &lB[j * 512]);
        }
    };
    stage(0);
    for (int kt = 0; kt < NT; ++kt) {
        __syncthreads();
        bf16x8 af[4], bfr[4];
        #pragma unroll
        for (int i = 0; i < 4; ++i) {
            af[i]  = *(const bf16x8*)&lA[(wr * 64 + i * 16 + l15) * 32 + l4 * 8];
            bfr[i] = *(const bf16x8*)&lB[(wc * 64 + i * 16 + l15) * 32 + l4 * 8];
        }
        __syncthreads();
        if (kt + 1 < NT) stage(kt + 1);
        #pragma unroll
        for (int i = 0; i < 4; ++i)
            #pragma unroll
            for (int j = 0; j < 4; ++j)
                acc[i][j] = __builtin_amdgcn_mfma_f32_16x16x32_bf16(af[i], bfr[j], acc[i][j], 0, 0, 0);
    }
    #pragma unroll
    for (int j = 0; j < 4; ++j) {
        int col = n0 + wc * 64 + j * 16 + l15;
        float bv = ext ? bias[col] : 0.f;
        #pragma unroll
        for (int i = 0; i < 4; ++i) {
            #pragma unroll
            for (int r = 0; r < 4; ++r) {
                int row = m0 + wr * 64 + i * 16 + l4 * 4 + r;
                float val = acc[i][j][r] + bv;
                if (ext) C32[(size_t)row * ldc + col] = val;
                else     C16[(size_t)row * ldc + col] = f2bf(val);
            }
        }
    }
}

// ---------------------------------------------------------------- attention
// Swapped QK^T + permuted K staging (P in registers), 2 q-fragments per wave
// (QBLK=128/block): each kf/vf ds_read feeds 2 MFMAs, barriers & staging per
// unit work halved, 2 independent chains of ILP. SCALE pre-folded into Wq
// (exact: 0.125 = 2^-3). Double-buffered K/V, 1 barrier/tile.
__global__ __launch_bounds__(256) void attn_kernel(const u16* __restrict__ qkv,
                                                   const u16* __restrict__ vT,
                                                   const float* __restrict__ mask,
                                                   u16* __restrict__ av) {
    __shared__ __align__(16) u16 lK[2][64 * 64];   // [kv][dh], rows permuted+swizzled
    __shared__ __align__(16) u16 lV[2][64 * 64];   // [dh][kv], swizzled
    int qt = blockIdx.x, bh = blockIdx.y;
    int b = bh >> 4, h = bh & 15;
    int tid = threadIdx.x, lane = tid & 63, wid = tid >> 6;
    int l4 = lane >> 4, l15 = lane & 15;
    int qw = qt * 128 + wid * 32;      // this wave's 32 q-rows

    const u16* qb0 = qkv + (size_t)(b * 2048 + qw + l15) * 3072 + h * 64;
    const u16* qb1 = qb0 + (size_t)16 * 3072;
    bf16x8 qf00 = *(const bf16x8*)&qb0[l4 * 8];
    bf16x8 qf01 = *(const bf16x8*)&qb0[32 + l4 * 8];
    bf16x8 qf10 = *(const bf16x8*)&qb1[l4 * 8];
    bf16x8 qf11 = *(const bf16x8*)&qb1[32 + l4 * 8];
    const float* mrow0 = mask + (size_t)(qw + l15) * 2048 + 8 * l4;
    const float* mrow1 = mrow0 + (size_t)16 * 2048;

    f32x4 o0[4] = {}, o1[4] = {};
    float lsum0 = 0.f, lsum1 = 0.f;

    // staging chunks: chunk c = 16B covering row c>>3, dh/kv (c&7)*8
    int c0 = tid, c1 = 256 + tid;
    // K-row permutation: QK^T C-frag k-order == PV A-frag k-order
    // (k = 32*(fj>>1) + 8*l4 + 4*(fj&1) + r)
    auto pmap = [](int g) {
        return (g & 32) + 4 * ((g >> 3) & 3) + (g & 3) + ((g & 4) << 2);
    };
    int kd0 = SWZB(pmap(c0 >> 3) * 128 + (c0 & 7) * 16);
    int kd1 = SWZB(pmap(c1 >> 3) * 128 + (c1 & 7) * 16);
    int vd0 = SWZB((c0 >> 3) * 128 + (c0 & 7) * 16);
    int vd1 = SWZB((c1 >> 3) * 128 + (c1 & 7) * 16);
    const u16* ksrc0 = qkv + (size_t)(b * 2048 + (c0 >> 3)) * 3072 + 1024 + h * 64 + (c0 & 7) * 8;
    const u16* ksrc1 = qkv + (size_t)(b * 2048 + (c1 >> 3)) * 3072 + 1024 + h * 64 + (c1 & 7) * 8;
    const u16* vsrc0 = vT + (size_t)(bh * 64 + (c0 >> 3)) * 2048 + (c0 & 7) * 8;
    const u16* vsrc1 = vT + (size_t)(bh * 64 + (c1 >> 3)) * 2048 + (c1 & 7) * 8;

    auto loadKV = [&](int t, bf16x8& K0, bf16x8& K1, bf16x8& V0, bf16x8& V1) {
        size_t ko = (size_t)t * (64 * 3072);
        int vo = t * 64;
        K0 = *(const bf16x8*)(ksrc0 + ko);
        K1 = *(const bf16x8*)(ksrc1 + ko);
        V0 = *(const bf16x8*)(vsrc0 + vo);
        V1 = *(const bf16x8*)(vsrc1 + vo);
    };

    union PU { u32 u[4]; bf16x8 v; };

    auto body = [&](int t, int pbuf,
                    bf16x8& cK0, bf16x8& cK1, bf16x8& cV0, bf16x8& cV1,
                    bf16x8& nK0, bf16x8& nK1, bf16x8& nV0, bf16x8& nV1) {
        // stage current tile (prev barrier guarantees buffer is free)
        *(bf16x8*)((char*)lK[pbuf] + kd0) = cK0;
        *(bf16x8*)((char*)lK[pbuf] + kd1) = cK1;
        *(bf16x8*)((char*)lV[pbuf] + vd0) = cV0;
        *(bf16x8*)((char*)lV[pbuf] + vd1) = cV1;
        __syncthreads();  // single barrier per tile (dbuf)
        if (t + 1 < 32) loadKV(t + 1, nK0, nK1, nV0, nV1);  // cross-tile prefetch
        int k0 = t * 64;
        // mask rows for both q-frags, issued before QK^T (latency under MFMA)
        f32x4 mm0[4], mm1[4];
        mm0[0] = *(const f32x4*)(mrow0 + k0);
        mm0[1] = *(const f32x4*)(mrow0 + k0 + 4);
        mm0[2] = *(const f32x4*)(mrow0 + k0 + 32);
        mm0[3] = *(const f32x4*)(mrow0 + k0 + 36);
        mm1[0] = *(const f32x4*)(mrow1 + k0);
        mm1[1] = *(const f32x4*)(mrow1 + k0 + 4);
        mm1[2] = *(const f32x4*)(mrow1 + k0 + 32);
        mm1[3] = *(const f32x4*)(mrow1 + k0 + 36);
        // S = mfma(K, Q): each kf pair feeds both q-frags
        const char* Kb = (const char*)lK[pbuf];
        f32x4 s0[4] = {}, s1[4] = {};
        __builtin_amdgcn_s_setprio(1);
        #pragma unroll
        for (int fj = 0; fj < 4; ++fj) {
            bf16x8 kf0 = *(const bf16x8*)(Kb + SWZB((fj * 16 + l15) * 128 + l4 * 16));
            bf16x8 kf1 = *(const bf16x8*)(Kb + SWZB((fj * 16 + l15) * 128 + 64 + l4 * 16));
            s0[fj] = __builtin_amdgcn_mfma_f32_16x16x32_bf16(kf0, qf00, s0[fj], 0, 0, 0);
            s0[fj] = __builtin_amdgcn_mfma_f32_16x16x32_bf16(kf1, qf01, s0[fj], 0, 0, 0);
            s1[fj] = __builtin_amdgcn_mfma_f32_16x16x32_bf16(kf0, qf10, s1[fj], 0, 0, 0);
            s1[fj] = __builtin_amdgcn_mfma_f32_16x16x32_bf16(kf1, qf11, s1[fj], 0, 0, 0);
        }
        __builtin_amdgcn_s_setprio(0);
        // P = exp(s*m) — SCALE already in Q; pack straight into PV A-frags
        PU pa0[2], pa1[2];
        #pragma unroll
        for (int fj = 0; fj < 4; ++fj) {
            float p0 = __expf(s0[fj][0] * mm0[fj][0]);
            float p1 = __expf(s0[fj][1] * mm0[fj][1]);
            float p2 = __expf(s0[fj][2] * mm0[fj][2]);
            float p3 = __expf(s0[fj][3] * mm0[fj][3]);
            lsum0 += (p0 + p1) + (p2 + p3);
            int ks = fj >> 1, hf = (fj & 1) * 2;
            pa0[ks].u[hf]     = cvtpk_bf16(p0, p1);
            pa0[ks].u[hf + 1] = cvtpk_bf16(p2, p3);
        }
        #pragma unroll
        for (int fj = 0; fj < 4; ++fj) {
            float p0 = __expf(s1[fj][0] * mm1[fj][0]);
            float p1 = __expf(s1[fj][1] * mm1[fj][1]);
            float p2 = __expf(s1[fj][2] * mm1[fj][2]);
            float p3 = __expf(s1[fj][3] * mm1[fj][3]);
            lsum1 += (p0 + p1) + (p2 + p3);
            int ks = fj >> 1, hf = (fj & 1) * 2;
            pa1[ks].u[hf]     = cvtpk_bf16(p0, p1);
            pa1[ks].u[hf + 1] = cvtpk_bf16(p2, p3);
        }
        // O += P V: each vf feeds both q-frags
        const char* Vb = (const char*)lV[pbuf];
        __builtin_amdgcn_s_setprio(1);
        #pragma unroll
        for (int ks = 0; ks < 2; ++ks) {
            #pragma unroll
            for (int fj = 0; fj < 4; ++fj) {
                bf16x8 vf = *(const bf16x8*)(Vb + SWZB((fj * 16 + l15) * 128 + ks * 64 + l4 * 16));
                o0[fj] = __builtin_amdgcn_mfma_f32_16x16x32_bf16(pa0[ks].v, vf, o0[fj], 0, 0, 0);
                o1[fj] = __builtin_amdgcn_mfma_f32_16x16x32_bf16(pa1[ks].v, vf, o1[fj], 0, 0, 0);
            }
        }
        __builtin_amdgcn_s_setprio(0);
    };

    bf16x8 ka0, ka1, va0, va1, kb0, kb1, vb0, vb1;
    loadKV(0, ka0, ka1, va0, va1);
    for (int t = 0; t < 32; t += 2) {
        body(t,     0, ka0, ka1, va0, va1, kb0, kb1, vb0, vb1);
        body(t + 1, 1, kb0, kb1, vb0, vb1, ka0, ka1, va0, va1);
    }

    // rowsums: reduce over the 4 l4-groups (same q=l15 column)
    lsum0 += __shfl_xor(lsum0, 16, 64);
    lsum0 += __shfl_xor(lsum0, 32, 64);
    lsum1 += __shfl_xor(lsum1, 16, 64);
    lsum1 += __shfl_xor(lsum1, 32, 64);
    float den0[4], den1[4];
    #pragma unroll
    for (int r = 0; r < 4; ++r) {
        den0[r] = __shfl(lsum0, l4 * 4 + r, 64);
        den1[r] = __shfl(lsum1, l4 * 4 + r, 64);
    }
    #pragma unroll
    for (int fj = 0; fj < 4; ++fj) {
        #pragma unroll
        for (int r = 0; r < 4; ++r) {
            int col = h * 64 + fj * 16 + l15;
            av[(size_t)(b * 2048 + qw + l4 * 4 + r) * 1024 + col]      = f2bf(o0[fj][r] / den0[r]);
            av[(size_t)(b * 2048 + qw + 16 + l4 * 4 + r) * 1024 + col] = f2bf(o1[fj][r] / den1[r]);
        }
    }
}

// ---------------------------------------------------------------- launch
extern "C" void kernel_launch(void* const* d_in, const int* in_sizes, int n_in,
                              void* d_out, int out_size, void* d_ws, size_t ws_size,
                              hipStream_t stream) {
    (void)in_sizes; (void)n_in; (void)out_size; (void)ws_size;
    const float* x     = (const float*)d_in[0];
    const float* mask  = (const float*)d_in[1];
    const float* gamma = (const float*)d_in[2];
    const float* beta  = (const float*)d_in[3];
    const float* Wq    = (const float*)d_in[4];
    const float* Wk    = (const float*)d_in[5];
    const float* Wv    = (const float*)d_in[6];
    const float* Wo    = (const float*)d_in[7];
    const float* bo    = (const float*)d_in[8];

    char* ws = (char*)d_ws;
    u16* xn   = (u16*)(ws);                                   // 16.8 MB (reused as av)
    u16* WT   = (u16*)(ws + 16777216);                        // 6.29 MB [3072][1024]
    u16* WoT  = (u16*)(ws + 16777216 + 6291456);              // 2.10 MB
    u16* qkvb = (u16*)(ws + 16777216 + 6291456 + 2097152);    // 50.33 MB [8192][3072]
    u16* vT   = (u16*)(ws + 16777216 + 6291456 + 2097152 + 50331648);  // 16.8 MB
    u16* av = xn;  // xn dead after QKV GEMM

    dim3 tb(256);
    // SCALE = 0.125 folded into Wq (exact bf16 exponent shift)
    transpose1024<<<dim3(16, 16), tb, 0, stream>>>(Wq, WT, 0.125f);
    transpose1024<<<dim3(16, 16), tb, 0, stream>>>(Wk, WT + 1024 * 1024, 1.0f);
    transpose1024<<<dim3(16, 16), tb, 0, stream>>>(Wv, WT + 2 * 1024 * 1024, 1.0f);
    transpose1024<<<dim3(16, 16), tb, 0, stream>>>(Wo, WoT, 1.0f);
    ln_kernel<<<8192, tb, 0, stream>>>(x, gamma, beta, xn);
    gemm_bt<<<dim3(24, 64), tb, 0, stream>>>(xn, WT, qkvb, nullptr, nullptr, 1024, 3072, 0);
    vtrans<<<dim3(32, 64), tb, 0, stream>>>(qkvb, vT);
    attn_kernel<<<dim3(16, 64), tb, 0, stream>>>(qkvb, vT, mask, av);
    gemm_bt<<<dim3(8, 64), tb, 0, stream>>>(av, WoT, nullptr, (float*)d_out, bo, 1024, 1024, 1);
}

// Round 9
// 280.258 us; speedup vs baseline: 1.0840x; 1.0135x over previous
//
#include <hip/hip_runtime.h>

typedef unsigned short u16;
typedef unsigned int u32;
typedef __bf16 bf16x8 __attribute__((ext_vector_type(8)));
typedef float f32x4 __attribute__((ext_vector_type(4)));

#define AS1 __attribute__((address_space(1)))
#define AS3 __attribute__((address_space(3)))

// XOR-swizzle for 128B-row LDS tiles (T2): flips byte bits 4-6 with row&7
#define SWZB(x) ((x) ^ ((((x) >> 7) & 7) << 4))

__device__ __forceinline__ float bf2f(u16 u) {
    union { u32 i; float f; } v; v.i = ((u32)u) << 16; return v.f;
}
__device__ __forceinline__ u16 f2bf(float f) {
    union { float f; u32 i; } v; v.f = f;
    u32 i = v.i;
    u32 r = (i + 0x7fffu + ((i >> 16) & 1u)) >> 16;
    return (u16)r;
}
__device__ __forceinline__ u32 cvtpk_bf16(float lo, float hi) {
    u32 r;
    asm("v_cvt_pk_bf16_f32 %0, %1, %2" : "=v"(r) : "v"(lo), "v"(hi));
    return r;
}
// raw 2^x (v_exp_f32); log2e pre-folded into Wq so softmax = exp2(s*m)
__device__ __forceinline__ float fexp2(float x) {
    float r;
    asm("v_exp_f32 %0, %1" : "=v"(r) : "v"(x));
    return r;
}
__device__ __forceinline__ void gload_lds16(const u16* src, u16* dst) {
    __builtin_amdgcn_global_load_lds((const AS1 void*)src, (AS3 void*)dst, 16, 0, 0);
}

// ---------------------------------------------------------------- transpose
// 1024x1024 fp32 -> bf16 transpose with scale: out[j][i] = (bf16)(in[i][j]*scale)
__global__ __launch_bounds__(256) void transpose1024(const float* __restrict__ in,
                                                     u16* __restrict__ out,
                                                     float scale) {
    __shared__ u16 t[64][65];
    int c = threadIdx.x & 63, r0 = threadIdx.x >> 6;
    int ib = blockIdx.y * 64, jb = blockIdx.x * 64;
    #pragma unroll
    for (int r = r0; r < 64; r += 4)
        t[r][c] = f2bf(in[(size_t)(ib + r) * 1024 + jb + c] * scale);
    __syncthreads();
    #pragma unroll
    for (int r = r0; r < 64; r += 4) out[(size_t)(jb + r) * 1024 + ib + c] = t[c][r];
}

// V transpose: qkv[(b*2048+t)*3072 + 2048 + h*64 + dh] -> vT[(bh*64+dh)*2048 + t]
__global__ __launch_bounds__(256) void vtrans(const u16* __restrict__ qkv,
                                              u16* __restrict__ vT) {
    int bh = blockIdx.y, b = bh >> 4, h = bh & 15;
    int t0 = blockIdx.x * 64;
    __shared__ u16 tl[64][65];
    int c = threadIdx.x & 63, r0 = threadIdx.x >> 6;
    const u16* src = qkv + ((size_t)(b * 2048 + t0)) * 3072 + 2048 + h * 64;
    #pragma unroll
    for (int r = r0; r < 64; r += 4) tl[r][c] = src[(size_t)r * 3072 + c];
    __syncthreads();
    u16* dst = vT + ((size_t)bh * 64) * 2048 + t0;
    #pragma unroll
    for (int r = r0; r < 64; r += 4) dst[(size_t)r * 2048 + c] = tl[c][r];
}

// ---------------------------------------------------------------- layernorm
__global__ __launch_bounds__(256) void ln_kernel(const float* __restrict__ x,
                                                 const float* __restrict__ g,
                                                 const float* __restrict__ bb,
                                                 u16* __restrict__ xn) {
    int row = blockIdx.x;
    int tid = threadIdx.x;
    const float* xr = x + (size_t)row * 1024;
    float4 v = *(const float4*)&xr[tid * 4];
    float f0 = v.x, f1 = v.y, f2 = v.z, f3 = v.w;
    float s = f0 + f1 + f2 + f3;
    float sq = f0 * f0 + f1 * f1 + f2 * f2 + f3 * f3;
    #pragma unroll
    for (int m = 1; m < 64; m <<= 1) { s += __shfl_xor(s, m, 64); sq += __shfl_xor(sq, m, 64); }
    __shared__ float red[8];
    int wid = tid >> 6, lane = tid & 63;
    if (lane == 0) { red[wid] = s; red[4 + wid] = sq; }
    __syncthreads();
    s = red[0] + red[1] + red[2] + red[3];
    sq = red[4] + red[5] + red[6] + red[7];
    float mu = s * (1.f / 1024.f);
    float var = sq * (1.f / 1024.f) - mu * mu;
    float rs = rsqrtf(var + 1e-5f);
    float4 gv = *(const float4*)&g[tid * 4];
    float4 bv = *(const float4*)&bb[tid * 4];
    ushort4 o;
    o.x = f2bf((f0 - mu) * rs * gv.x + bv.x);
    o.y = f2bf((f1 - mu) * rs * gv.y + bv.y);
    o.z = f2bf((f2 - mu) * rs * gv.z + bv.z);
    o.w = f2bf((f3 - mu) * rs * gv.w + bv.w);
    *(ushort4*)&xn[(size_t)row * 1024 + tid * 4] = o;
}

// ---------------------------------------------------------------- GEMM (B^T)
// C[m][n] = sum_k A[m][k]*BT[n][k]; ext=0: bf16 out; ext=1: fp32 out + bias.
__global__ __launch_bounds__(256) void gemm_bt(const u16* __restrict__ A,
                                               const u16* __restrict__ BT,
                                               u16* __restrict__ C16,
                                               float* __restrict__ C32,
                                               const float* __restrict__ bias,
                                               int K, int ldc, int ext) {
    __shared__ __align__(16) u16 lA[128 * 32];
    __shared__ __align__(16) u16 lB[128 * 32];
    int tid = threadIdx.x, lane = tid & 63, wid = tid >> 6;
    int wr = wid >> 1, wc = wid & 1;
    int m0 = blockIdx.y * 128, n0 = blockIdx.x * 128;
    int l4 = lane >> 4, l15 = lane & 15;

    f32x4 acc[4][4] = {};
    int NT = K >> 5;

    auto stage = [&](int kt) {
        int k0 = kt << 5;
        #pragma unroll
        for (int i = 0; i < 2; ++i) {
            int j = wid * 2 + i;
            int row = j * 16 + (lane >> 2);
            int ch = (lane & 3) * 8;
            gload_lds16(A + (size_t)(m0 + row) * K + k0 + ch, &lA[j * 512]);
            gload_lds16(BT + (size_t)(n0 + row) * K + k0 + ch, &lB[j * 512]);
        }
    };
    stage(0);
    for (int kt = 0; kt < NT; ++kt) {
        __syncthreads();
        bf16x8 af[4], bfr[4];
        #pragma unroll
        for (int i = 0; i < 4; ++i) {
            af[i]  = *(const bf16x8*)&lA[(wr * 64 + i * 16 + l15) * 32 + l4 * 8];
            bfr[i] = *(const bf16x8*)&lB[(wc * 64 + i * 16 + l15) * 32 + l4 * 8];
        }
        __syncthreads();
        if (kt + 1 < NT) stage(kt + 1);
        #pragma unroll
        for (int i = 0; i < 4; ++i)
            #pragma unroll
            for (int j = 0; j < 4; ++j)
                acc[i][j] = __builtin_amdgcn_mfma_f32_16x16x32_bf16(af[i], bfr[j], acc[i][j], 0, 0, 0);
    }
    #pragma unroll
    for (int j = 0; j < 4; ++j) {
        int col = n0 + wc * 64 + j * 16 + l15;
        float bv = ext ? bias[col] : 0.f;
        #pragma unroll
        for (int i = 0; i < 4; ++i) {
            #pragma unroll
            for (int r = 0; r < 4; ++r) {
                int row = m0 + wr * 64 + i * 16 + l4 * 4 + r;
                float val = acc[i][j][r] + bv;
                if (ext) C32[(size_t)row * ldc + col] = val;
                else     C16[(size_t)row * ldc + col] = f2bf(val);
            }
        }
    }
}

// ---------------------------------------------------------------- attention
// Swapped QK^T + permuted K staging (P in registers), 2 q-frags/wave,
// SCALE*log2e folded into Wq so softmax = v_exp_f32(s*m).
// Pipelined body: QKT(t) -> exp(t) -> stage(t+1) -> load(t+2) -> PV(t) -> bar
// (stage/load overlap exp+PV; 1 barrier/tile, double-buffered LDS).
__global__ __launch_bounds__(256) void attn_kernel(const u16* __restrict__ qkv,
                                                   const u16* __restrict__ vT,
                                                   const float* __restrict__ mask,
                                                   u16* __restrict__ av) {
    __shared__ __align__(16) u16 lK[2][64 * 64];   // [kv][dh], rows permuted+swizzled
    __shared__ __align__(16) u16 lV[2][64 * 64];   // [dh][kv], swizzled
    int qt = blockIdx.x, bh = blockIdx.y;
    int b = bh >> 4, h = bh & 15;
    int tid = threadIdx.x, lane = tid & 63, wid = tid >> 6;
    int l4 = lane >> 4, l15 = lane & 15;
    int qw = qt * 128 + wid * 32;      // this wave's 32 q-rows

    const u16* qb0 = qkv + (size_t)(b * 2048 + qw + l15) * 3072 + h * 64;
    const u16* qb1 = qb0 + (size_t)16 * 3072;
    bf16x8 qf00 = *(const bf16x8*)&qb0[l4 * 8];
    bf16x8 qf01 = *(const bf16x8*)&qb0[32 + l4 * 8];
    bf16x8 qf10 = *(const bf16x8*)&qb1[l4 * 8];
    bf16x8 qf11 = *(const bf16x8*)&qb1[32 + l4 * 8];
    const float* mrow0 = mask + (size_t)(qw + l15) * 2048 + 8 * l4;
    const float* mrow1 = mrow0 + (size_t)16 * 2048;

    f32x4 o0[4] = {}, o1[4] = {};
    float lsum0 = 0.f, lsum1 = 0.f;

    // staging chunks: chunk c = 16B covering row c>>3, dh/kv (c&7)*8
    int c0 = tid, c1 = 256 + tid;
    // K-row permutation: QK^T C-frag k-order == PV A-frag k-order
    auto pmap = [](int g) {
        return (g & 32) + 4 * ((g >> 3) & 3) + (g & 3) + ((g & 4) << 2);
    };
    int kd0 = SWZB(pmap(c0 >> 3) * 128 + (c0 & 7) * 16);
    int kd1 = SWZB(pmap(c1 >> 3) * 128 + (c1 & 7) * 16);
    int vd0 = SWZB((c0 >> 3) * 128 + (c0 & 7) * 16);
    int vd1 = SWZB((c1 >> 3) * 128 + (c1 & 7) * 16);
    const u16* ksrc0 = qkv + (size_t)(b * 2048 + (c0 >> 3)) * 3072 + 1024 + h * 64 + (c0 & 7) * 8;
    const u16* ksrc1 = qkv + (size_t)(b * 2048 + (c1 >> 3)) * 3072 + 1024 + h * 64 + (c1 & 7) * 8;
    const u16* vsrc0 = vT + (size_t)(bh * 64 + (c0 >> 3)) * 2048 + (c0 & 7) * 8;
    const u16* vsrc1 = vT + (size_t)(bh * 64 + (c1 >> 3)) * 2048 + (c1 & 7) * 8;

    auto loadKV = [&](int t, bf16x8& K0, bf16x8& K1, bf16x8& V0, bf16x8& V1) {
        size_t ko = (size_t)t * (64 * 3072);
        int vo = t * 64;
        K0 = *(const bf16x8*)(ksrc0 + ko);
        K1 = *(const bf16x8*)(ksrc1 + ko);
        V0 = *(const bf16x8*)(vsrc0 + vo);
        V1 = *(const bf16x8*)(vsrc1 + vo);
    };

    union PU { u32 u[4]; bf16x8 v; };

    // body: tile t lives in buf[t&1]; nxt holds tile t+1's regs (staged here);
    // free gets tile t+2's loads issued into it.
    auto body = [&](int t, int pbuf,
                    bf16x8& nK0, bf16x8& nK1, bf16x8& nV0, bf16x8& nV1,
                    bf16x8& fK0, bf16x8& fK1, bf16x8& fV0, bf16x8& fV1) {
        int k0 = t * 64;
        // mask loads for this tile (cover under QK^T)
        f32x4 mm0[4], mm1[4];
        mm0[0] = *(const f32x4*)(mrow0 + k0);
        mm0[1] = *(const f32x4*)(mrow0 + k0 + 4);
        mm0[2] = *(const f32x4*)(mrow0 + k0 + 32);
        mm0[3] = *(const f32x4*)(mrow0 + k0 + 36);
        mm1[0] = *(const f32x4*)(mrow1 + k0);
        mm1[1] = *(const f32x4*)(mrow1 + k0 + 4);
        mm1[2] = *(const f32x4*)(mrow1 + k0 + 32);
        mm1[3] = *(const f32x4*)(mrow1 + k0 + 36);
        // S = mfma(K, Q)
        const char* Kb = (const char*)lK[pbuf];
        f32x4 s0[4] = {}, s1[4] = {};
        __builtin_amdgcn_s_setprio(1);
        #pragma unroll
        for (int fj = 0; fj < 4; ++fj) {
            bf16x8 kf0 = *(const bf16x8*)(Kb + SWZB((fj * 16 + l15) * 128 + l4 * 16));
            bf16x8 kf1 = *(const bf16x8*)(Kb + SWZB((fj * 16 + l15) * 128 + 64 + l4 * 16));
            s0[fj] = __builtin_amdgcn_mfma_f32_16x16x32_bf16(kf0, qf00, s0[fj], 0, 0, 0);
            s0[fj] = __builtin_amdgcn_mfma_f32_16x16x32_bf16(kf1, qf01, s0[fj], 0, 0, 0);
            s1[fj] = __builtin_amdgcn_mfma_f32_16x16x32_bf16(kf0, qf10, s1[fj], 0, 0, 0);
            s1[fj] = __builtin_amdgcn_mfma_f32_16x16x32_bf16(kf1, qf11, s1[fj], 0, 0, 0);
        }
        __builtin_amdgcn_s_setprio(0);
        // P = exp2(s*m) (SCALE*log2e in Q), packed into PV A-frags
        PU pa0[2], pa1[2];
        #pragma unroll
        for (int fj = 0; fj < 4; ++fj) {
            float p0 = fexp2(s0[fj][0] * mm0[fj][0]);
            float p1 = fexp2(s0[fj][1] * mm0[fj][1]);
            float p2 = fexp2(s0[fj][2] * mm0[fj][2]);
            float p3 = fexp2(s0[fj][3] * mm0[fj][3]);
            lsum0 += (p0 + p1) + (p2 + p3);
            int ks = fj >> 1, hf = (fj & 1) * 2;
            pa0[ks].u[hf]     = cvtpk_bf16(p0, p1);
            pa0[ks].u[hf + 1] = cvtpk_bf16(p2, p3);
        }
        #pragma unroll
        for (int fj = 0; fj < 4; ++fj) {
            float p0 = fexp2(s1[fj][0] * mm1[fj][0]);
            float p1 = fexp2(s1[fj][1] * mm1[fj][1]);
            float p2 = fexp2(s1[fj][2] * mm1[fj][2]);
            float p3 = fexp2(s1[fj][3] * mm1[fj][3]);
            lsum1 += (p0 + p1) + (p2 + p3);
            int ks = fj >> 1, hf = (fj & 1) * 2;
            pa1[ks].u[hf]     = cvtpk_bf16(p0, p1);
            pa1[ks].u[hf + 1] = cvtpk_bf16(p2, p3);
        }
        // stage tile t+1 into the other buffer (its last readers passed bar(t-1))
        if (t + 1 < 32) {
            char* Kn = (char*)lK[pbuf ^ 1];
            char* Vn = (char*)lV[pbuf ^ 1];
            *(bf16x8*)(Kn + kd0) = nK0;
            *(bf16x8*)(Kn + kd1) = nK1;
            *(bf16x8*)(Vn + vd0) = nV0;
            *(bf16x8*)(Vn + vd1) = nV1;
        }
        // issue tile t+2 loads (in flight across PV + bar + QKT(t+1))
        if (t + 2 < 32) loadKV(t + 2, fK0, fK1, fV0, fV1);
        // O += P V
        const char* Vb = (const char*)lV[pbuf];
        __builtin_amdgcn_s_setprio(1);
        #pragma unroll
        for (int ks = 0; ks < 2; ++ks) {
            #pragma unroll
            for (int fj = 0; fj < 4; ++fj) {
                bf16x8 vf = *(const bf16x8*)(Vb + SWZB((fj * 16 + l15) * 128 + ks * 64 + l4 * 16));
                o0[fj] = __builtin_amdgcn_mfma_f32_16x16x32_bf16(pa0[ks].v, vf, o0[fj], 0, 0, 0);
                o1[fj] = __builtin_amdgcn_mfma_f32_16x16x32_bf16(pa1[ks].v, vf, o1[fj], 0, 0, 0);
            }
        }
        __builtin_amdgcn_s_setprio(0);
        __syncthreads();  // tile t+1 staged & visible; buffers rotate
    };

    bf16x8 ka0, ka1, va0, va1, kb0, kb1, vb0, vb1;
    // prologue: tile0 -> buf0, tile1 regs in flight
    loadKV(0, ka0, ka1, va0, va1);
    *(bf16x8*)((char*)lK[0] + kd0) = ka0;
    *(bf16x8*)((char*)lK[0] + kd1) = ka1;
    *(bf16x8*)((char*)lV[0] + vd0) = va0;
    *(bf16x8*)((char*)lV[0] + vd1) = va1;
    loadKV(1, kb0, kb1, vb0, vb1);
    __syncthreads();
    for (int t = 0; t < 32; t += 2) {
        // even: tile t in buf0, t+1 regs in b, t+2 loads into a
        body(t,     0, kb0, kb1, vb0, vb1, ka0, ka1, va0, va1);
        // odd: tile t+1 in buf1, t+2 regs in a, t+3 loads into b
        body(t + 1, 1, ka0, ka1, va0, va1, kb0, kb1, vb0, vb1);
    }

    // rowsums: reduce over the 4 l4-groups (same q=l15 column)
    lsum0 += __shfl_xor(lsum0, 16, 64);
    lsum0 += __shfl_xor(lsum0, 32, 64);
    lsum1 += __shfl_xor(lsum1, 16, 64);
    lsum1 += __shfl_xor(lsum1, 32, 64);
    float den0[4], den1[4];
    #pragma unroll
    for (int r = 0; r < 4; ++r) {
        den0[r] = __shfl(lsum0, l4 * 4 + r, 64);
        den1[r] = __shfl(lsum1, l4 * 4 + r, 64);
    }
    #pragma unroll
    for (int fj = 0; fj < 4; ++fj) {
        #pragma unroll
        for (int r = 0; r < 4; ++r) {
            int col = h * 64 + fj * 16 + l15;
            av[(size_t)(b * 2048 + qw + l4 * 4 + r) * 1024 + col]      = f2bf(o0[fj][r] / den0[r]);
            av[(size_t)(b * 2048 + qw + 16 + l4 * 4 + r) * 1024 + col] = f2bf(o1[fj][r] / den1[r]);
        }
    }
}

// ---------------------------------------------------------------- launch
extern "C" void kernel_launch(void* const* d_in, const int* in_sizes, int n_in,
                              void* d_out, int out_size, void* d_ws, size_t ws_size,
                              hipStream_t stream) {
    (void)in_sizes; (void)n_in; (void)out_size; (void)ws_size;
    const float* x     = (const float*)d_in[0];
    const float* mask  = (const float*)d_in[1];
    const float* gamma = (const float*)d_in[2];
    const float* beta  = (const float*)d_in[3];
    const float* Wq    = (const float*)d_in[4];
    const float* Wk    = (const float*)d_in[5];
    const float* Wv    = (const float*)d_in[6];
    const float* Wo    = (const float*)d_in[7];
    const float* bo    = (const float*)d_in[8];

    char* ws = (char*)d_ws;
    u16* xn   = (u16*)(ws);                                   // 16.8 MB (reused as av)
    u16* WT   = (u16*)(ws + 16777216);                        // 6.29 MB [3072][1024]
    u16* WoT  = (u16*)(ws + 16777216 + 6291456);              // 2.10 MB
    u16* qkvb = (u16*)(ws + 16777216 + 6291456 + 2097152);    // 50.33 MB [8192][3072]
    u16* vT   = (u16*)(ws + 16777216 + 6291456 + 2097152 + 50331648);  // 16.8 MB
    u16* av = xn;  // xn dead after QKV GEMM

    dim3 tb(256);
    // SCALE*log2e = 0.125 * 1.4426950 folded into Wq (softmax uses raw v_exp_f32)
    transpose1024<<<dim3(16, 16), tb, 0, stream>>>(Wq, WT, 0.18033688f);
    transpose1024<<<dim3(16, 16), tb, 0, stream>>>(Wk, WT + 1024 * 1024, 1.0f);
    transpose1024<<<dim3(16, 16), tb, 0, stream>>>(Wv, WT + 2 * 1024 * 1024, 1.0f);
    transpose1024<<<dim3(16, 16), tb, 0, stream>>>(Wo, WoT, 1.0f);
    ln_kernel<<<8192, tb, 0, stream>>>(x, gamma, beta, xn);
    gemm_bt<<<dim3(24, 64), tb, 0, stream>>>(xn, WT, qkvb, nullptr, nullptr, 1024, 3072, 0);
    vtrans<<<dim3(32, 64), tb, 0, stream>>>(qkvb, vT);
    attn_kernel<<<dim3(16, 64), tb, 0, stream>>>(qkvb, vT, mask, av);
    gemm_bt<<<dim3(8, 64), tb, 0, stream>>>(av, WoT, nullptr, (float*)d_out, bo, 1024, 1024, 1);
}